// Round 14
// baseline (225.939 us; speedup 1.0000x reference)
//
#include <hip/hip_runtime.h>

#define N_NODES 100000
#define N_EDGES 1600000
constexpr int BLK = 256;
constexpr int NBKT = (N_NODES + 127) / 128;   // 782 buckets of 128 nodes
constexpr int PACK_SHIFT = 17;                // src < 2^17
constexpr int EPT = 16;                       // edges/thread in scatter
constexpr int EPBLK = BLK * EPT;              // 4096
constexpr int NSCAT = (N_EDGES + EPBLK - 1) / EPBLK;   // 391

// ---------- bf16 helpers (RTNE) ----------
__device__ __forceinline__ unsigned short f2bf(float f) {
    unsigned int u = __float_as_uint(f);
    u = (u + 0x7FFFu + ((u >> 16) & 1u)) >> 16;
    return (unsigned short)u;
}
__device__ __forceinline__ float bf2f(unsigned short s) {
    return __uint_as_float(((unsigned int)s) << 16);
}

// ---------- edge dtype detection (int32 vs int64-lowword) ----------
__global__ void detect_idx64(const unsigned int* __restrict__ e, int* __restrict__ flag) {
    if (blockIdx.x == 0 && threadIdx.x == 0) {
        int is64 = 1;
        for (int i = 0; i < 64; ++i) if (e[2 * i + 1] != 0u) { is64 = 0; break; }
        *flag = is64;
    }
}

__device__ __forceinline__ int load_dst(const int* e, int f, int i) {
    return f ? e[2 * (N_EDGES + i)] : e[N_EDGES + i];
}
__device__ __forceinline__ int load_src(const int* e, int f, int i) {
    return f ? e[2 * i] : e[i];
}

// ---------- pass A: coarse bucket histogram (LDS-staged) ----------
__global__ void bucket_hist(const int* __restrict__ eraw, const int* __restrict__ flag,
                            int* __restrict__ bhist) {
    __shared__ int h[NBKT];
    for (int i = threadIdx.x; i < NBKT; i += BLK) h[i] = 0;
    __syncthreads();
    const int f = *flag;
    const int stride = gridDim.x * BLK;
    for (int i = blockIdx.x * BLK + threadIdx.x; i < N_EDGES; i += stride)
        atomicAdd(&h[load_dst(eraw, f, i) >> 7], 1);
    __syncthreads();
    for (int i = threadIdx.x; i < NBKT; i += BLK) {
        const int v = h[i];
        if (v) atomicAdd(&bhist[i], v);
    }
}

// ---------- single-block exclusive scan of bucket counts ----------
__global__ void scan_buckets(const int* __restrict__ bhist, int* __restrict__ base,
                             int* __restrict__ cursor) {
    __shared__ int tmp[1024];
    const int t = threadIdx.x;
    const int v = (t < NBKT) ? bhist[t] : 0;
    tmp[t] = v;
    __syncthreads();
    for (int off = 1; off < 1024; off <<= 1) {
        const int u = (t >= off) ? tmp[t - off] : 0;
        __syncthreads();
        tmp[t] += u;
        __syncthreads();
    }
    if (t < NBKT) {
        const int b = tmp[t] - v;   // exclusive
        base[t] = b;
        cursor[t] = b;
    }
    if (t == 0) base[NBKT] = N_EDGES;
}

// ---------- pass B: block-aggregated scatter into bucket order ----------
__global__ void bucket_scatter(const int* __restrict__ eraw, const int* __restrict__ flag,
                               int* __restrict__ cursor, int* __restrict__ ebkt) {
    __shared__ int h[NBKT];
    const int f = *flag;
    const int e0 = blockIdx.x * EPBLK;
    for (int i = threadIdx.x; i < NBKT; i += BLK) h[i] = 0;
    __syncthreads();
    int bs[EPT], ps[EPT];
#pragma unroll
    for (int k = 0; k < EPT; ++k) {
        const int i = e0 + k * BLK + threadIdx.x;
        if (i < N_EDGES) {
            const int d = load_dst(eraw, f, i);
            const int s = load_src(eraw, f, i);
            bs[k] = d >> 7;
            ps[k] = s | ((d & 127) << PACK_SHIFT);
            atomicAdd(&h[bs[k]], 1);
        } else {
            bs[k] = -1;
            ps[k] = 0;
        }
    }
    __syncthreads();
    for (int b = threadIdx.x; b < NBKT; b += BLK) {
        const int c = h[b];
        if (c) h[b] = atomicAdd(&cursor[b], c);
    }
    __syncthreads();
#pragma unroll
    for (int k = 0; k < EPT; ++k) {
        if (bs[k] >= 0) {
            const int pos = atomicAdd(&h[bs[k]], 1);
            ebkt[pos] = ps[k];
        }
    }
}

// ---------- pass C: per-bucket CSR-ify (dense contiguous writes) ----------
__global__ void csrify(const int* __restrict__ base, const int* __restrict__ ebkt,
                       int* __restrict__ adj, int* __restrict__ rowptr,
                       int* __restrict__ deg) {
    __shared__ int hist[128];
    __shared__ int excl[128];
    __shared__ int lcur[128];
    const int b = blockIdx.x;
    const int s0 = base[b], s1 = base[b + 1];
    for (int i = threadIdx.x; i < 128; i += BLK) hist[i] = 0;
    __syncthreads();
    for (int i = s0 + threadIdx.x; i < s1; i += BLK)
        atomicAdd(&hist[ebkt[i] >> PACK_SHIFT], 1);
    __syncthreads();
    if (threadIdx.x < 128) excl[threadIdx.x] = hist[threadIdx.x];
    __syncthreads();
    for (int off = 1; off < 128; off <<= 1) {
        int t = 0;
        if (threadIdx.x < 128 && threadIdx.x >= off) t = excl[threadIdx.x - off];
        __syncthreads();
        if (threadIdx.x < 128) excl[threadIdx.x] += t;
        __syncthreads();
    }
    if (threadIdx.x < 128) {
        const int e = excl[threadIdx.x] - hist[threadIdx.x];   // exclusive
        lcur[threadIdx.x] = s0 + e;
        const int node = b * 128 + threadIdx.x;
        if (node < N_NODES) {
            rowptr[node] = s0 + e;
            deg[node] = hist[threadIdx.x];
        }
    }
    __syncthreads();
    for (int i = s0 + threadIdx.x; i < s1; i += BLK) {
        const int p = ebkt[i];
        const int pos = atomicAdd(&lcur[p >> PACK_SHIFT], 1);
        adj[pos] = p & ((1 << PACK_SHIFT) - 1);
    }
}

// ---------- helpers ----------
__device__ __forceinline__ void fma_step(float4& acc, float xs, float4 w) {
    acc.x = fmaf(xs, w.x, acc.x);
    acc.y = fmaf(xs, w.y, acc.y);
    acc.z = fmaf(xs, w.z, acc.z);
    acc.w = fmaf(xs, w.w, acc.w);
}

__device__ __forceinline__ void add4(float4& a, float4 v) {
    a.x += v.x; a.y += v.y; a.z += v.z; a.w += v.w;
}

__device__ __forceinline__ void addbf4(float4& a, ushort4 t) {
    a.x += bf2f(t.x); a.y += bf2f(t.y); a.z += bf2f(t.z); a.w += bf2f(t.w);
}

// ---------- Y[n,C] = X[n,K] @ W[K,C] + b, x LDS-staged; also writes bf16 copy ----------
// launched with exactly n/NPB blocks
template<int K, int C>
__global__ void gemm_bias(const float* __restrict__ X, const float* __restrict__ W,
                          const float* __restrict__ bias, float* __restrict__ Y,
                          unsigned short* __restrict__ Yb, int n) {
    constexpr int CQ = C / 4;       // channel quads
    constexpr int NPB = BLK / CQ;   // nodes per block
    constexpr int KQ = K / 4;       // k quads per row
    __shared__ float4 Ws[K * CQ];
    __shared__ float4 xL[NPB * KQ];   // row r rotated by r quads
    for (int i = threadIdx.x; i < K * CQ; i += BLK)
        Ws[i] = reinterpret_cast<const float4*>(W)[i];
    const int cq = threadIdx.x % CQ;
    const int ns = threadIdx.x / CQ;
    const float4 bv = reinterpret_cast<const float4*>(bias)[cq];
    const float4* X4 = reinterpret_cast<const float4*>(X);
    const int tile = blockIdx.x;
    for (int i = threadIdx.x; i < NPB * KQ; i += BLK) {
        const int r = i / KQ;
        const int k4 = i % KQ;
        xL[r * KQ + ((k4 + r) % KQ)] = X4[(size_t)(tile * NPB + r) * KQ + k4];
    }
    __syncthreads();
    const float4* xr = &xL[ns * KQ];
    float4 acc = bv;
#pragma unroll 4
    for (int k4 = 0; k4 < KQ; ++k4) {
        float4 xv = xr[(k4 + ns) % KQ];
        fma_step(acc, xv.x, Ws[(4 * k4 + 0) * CQ + cq]);
        fma_step(acc, xv.y, Ws[(4 * k4 + 1) * CQ + cq]);
        fma_step(acc, xv.z, Ws[(4 * k4 + 2) * CQ + cq]);
        fma_step(acc, xv.w, Ws[(4 * k4 + 3) * CQ + cq]);
    }
    const size_t oi = (size_t)(tile * NPB + ns) * CQ + cq;
    reinterpret_cast<float4*>(Y)[oi] = acc;
    ushort4 bfv;
    bfv.x = f2bf(acc.x); bfv.y = f2bf(acc.y);
    bfv.z = f2bf(acc.z); bfv.w = f2bf(acc.w);
    reinterpret_cast<ushort4*>(Yb)[oi] = bfv;
}

// ---------- fused: conv1 gather-update (h1) + conv2 lin2 (h2pre) ----------
// TPB=1024, NPB=64. LDS: Ws 32KB + Ws2 8KB + Ag 17.4KB + H1 17.4KB ~ 74KB -> 2 blocks/CU.
// Writes h2pre (fp32 + bf16) directly; h1 never touches global memory.
template<int KH, int C, int TPB>
__global__ void update_gather_fused(const float* __restrict__ P,
                                    const unsigned short* __restrict__ Pb,
                                    const int* __restrict__ rowptr, const int* __restrict__ cnt,
                                    const int* __restrict__ adj,
                                    const float* __restrict__ W, const float* __restrict__ bias,
                                    const float* __restrict__ W2, const float* __restrict__ b2,
                                    float* __restrict__ Y2, unsigned short* __restrict__ Y2b,
                                    int n) {
    constexpr int CQ = C / 4;            // 16 lanes per node
    constexpr int NPB = TPB / CQ;        // 64 nodes per block
    constexpr int K = 2 * KH;
    __shared__ float4 Ws[K * CQ];        // 32 KB: W1_1
    __shared__ float2 Ws2[64 * 16];      // 8 KB:  W2_2 (64x32) as float2 pairs
    __shared__ float4 Ag[NPB][CQ + 1];   // padded
    __shared__ float4 H1[NPB][CQ + 1];   // relu'd h1 exchange
    for (int i = threadIdx.x; i < K * CQ; i += TPB)
        Ws[i] = reinterpret_cast<const float4*>(W)[i];
    for (int i = threadIdx.x; i < 64 * 16; i += TPB)
        Ws2[i] = reinterpret_cast<const float2*>(W2)[i];
    __syncthreads();
    const int cq = threadIdx.x % CQ;
    const int ns = threadIdx.x / CQ;
    const float4 bv = reinterpret_cast<const float4*>(bias)[cq];
    const float2 b2v = reinterpret_cast<const float2*>(b2)[cq];
    const float4* P4 = reinterpret_cast<const float4*>(P);
    const ushort4* Pb4 = reinterpret_cast<const ushort4*>(Pb);
    const int nodeRaw = blockIdx.x * NPB + ns;
    const bool active = nodeRaw < n;
    const int node = active ? nodeRaw : (n - 1);
    const int start = rowptr[node];
    const int deg = cnt[node];
    const float inv = 1.0f / (float)(deg + 1);
    const float4* pr = &P4[(size_t)node * CQ];

    // gather-sum neighbors (bf16 rows), 8 loads in flight
    float4 agg = {0.f, 0.f, 0.f, 0.f};
    int j = 0;
    for (; j + 7 < deg; j += 8) {
        const int s0 = adj[start + j];
        const int s1 = adj[start + j + 1];
        const int s2 = adj[start + j + 2];
        const int s3 = adj[start + j + 3];
        const int s4 = adj[start + j + 4];
        const int s5 = adj[start + j + 5];
        const int s6 = adj[start + j + 6];
        const int s7 = adj[start + j + 7];
        const ushort4 t0 = Pb4[(size_t)s0 * CQ + cq];
        const ushort4 t1 = Pb4[(size_t)s1 * CQ + cq];
        const ushort4 t2 = Pb4[(size_t)s2 * CQ + cq];
        const ushort4 t3 = Pb4[(size_t)s3 * CQ + cq];
        const ushort4 t4 = Pb4[(size_t)s4 * CQ + cq];
        const ushort4 t5 = Pb4[(size_t)s5 * CQ + cq];
        const ushort4 t6 = Pb4[(size_t)s6 * CQ + cq];
        const ushort4 t7 = Pb4[(size_t)s7 * CQ + cq];
        addbf4(agg, t0); addbf4(agg, t1); addbf4(agg, t2); addbf4(agg, t3);
        addbf4(agg, t4); addbf4(agg, t5); addbf4(agg, t6); addbf4(agg, t7);
    }
    if (j + 3 < deg) {
        const int s0 = adj[start + j];
        const int s1 = adj[start + j + 1];
        const int s2 = adj[start + j + 2];
        const int s3 = adj[start + j + 3];
        const ushort4 t0 = Pb4[(size_t)s0 * CQ + cq];
        const ushort4 t1 = Pb4[(size_t)s1 * CQ + cq];
        const ushort4 t2 = Pb4[(size_t)s2 * CQ + cq];
        const ushort4 t3 = Pb4[(size_t)s3 * CQ + cq];
        addbf4(agg, t0); addbf4(agg, t1); addbf4(agg, t2); addbf4(agg, t3);
        j += 4;
    }
    for (; j < deg; ++j)
        addbf4(agg, Pb4[(size_t)adj[start + j] * CQ + cq]);

    float4 acc = bv;
#pragma unroll 4
    for (int k4 = 0; k4 < KH / 4; ++k4) {
        float4 pv = pr[k4];
        fma_step(acc, pv.x, Ws[(4 * k4 + 0) * CQ + cq]);
        fma_step(acc, pv.y, Ws[(4 * k4 + 1) * CQ + cq]);
        fma_step(acc, pv.z, Ws[(4 * k4 + 2) * CQ + cq]);
        fma_step(acc, pv.w, Ws[(4 * k4 + 3) * CQ + cq]);
    }
    {
        float4 pv = pr[cq];
        add4(agg, pv);
        agg.x *= inv; agg.y *= inv; agg.z *= inv; agg.w *= inv;
    }
    Ag[ns][cq] = agg;
    __syncthreads();
#pragma unroll 4
    for (int k4 = 0; k4 < KH / 4; ++k4) {
        float4 av = Ag[ns][k4];
        fma_step(acc, av.x, Ws[(KH + 4 * k4 + 0) * CQ + cq]);
        fma_step(acc, av.y, Ws[(KH + 4 * k4 + 1) * CQ + cq]);
        fma_step(acc, av.z, Ws[(KH + 4 * k4 + 2) * CQ + cq]);
        fma_step(acc, av.w, Ws[(KH + 4 * k4 + 3) * CQ + cq]);
    }
    acc.x = fmaxf(acc.x, 0.0f);
    acc.y = fmaxf(acc.y, 0.0f);
    acc.z = fmaxf(acc.z, 0.0f);
    acc.w = fmaxf(acc.w, 0.0f);

    // ---- fused conv2 lin2: h2pre = h1 @ W2 + b2 (no relu) ----
    H1[ns][cq] = acc;
    __syncthreads();
    float a0 = b2v.x, a1 = b2v.y;   // this lane owns channels 2cq, 2cq+1
#pragma unroll
    for (int k4 = 0; k4 < 16; ++k4) {
        const float4 h = H1[ns][k4];          // broadcast within node group
        const float2 w0 = Ws2[(4 * k4 + 0) * 16 + cq];
        const float2 w1 = Ws2[(4 * k4 + 1) * 16 + cq];
        const float2 w2 = Ws2[(4 * k4 + 2) * 16 + cq];
        const float2 w3 = Ws2[(4 * k4 + 3) * 16 + cq];
        a0 = fmaf(h.x, w0.x, a0); a1 = fmaf(h.x, w0.y, a1);
        a0 = fmaf(h.y, w1.x, a0); a1 = fmaf(h.y, w1.y, a1);
        a0 = fmaf(h.z, w2.x, a0); a1 = fmaf(h.z, w2.y, a1);
        a0 = fmaf(h.w, w3.x, a0); a1 = fmaf(h.w, w3.y, a1);
    }
    if (active) {
        float2 o; o.x = a0; o.y = a1;
        reinterpret_cast<float2*>(Y2)[(size_t)nodeRaw * 16 + cq] = o;
        ushort2 ob; ob.x = f2bf(a0); ob.y = f2bf(a1);
        reinterpret_cast<ushort2*>(Y2b)[(size_t)nodeRaw * 16 + cq] = ob;
    }
}

// ---------- conv2 update (bf16 ushort4 gather) fused with final 32->1 linear ----------
// CQ=8 lanes/node (float4 out channels), NPB=32 nodes/block; launched with n/32 blocks
__global__ void update2_final(const float* __restrict__ P,
                              const unsigned short* __restrict__ Pb,
                              const int* __restrict__ rowptr, const int* __restrict__ cnt,
                              const int* __restrict__ adj,
                              const float* __restrict__ W, const float* __restrict__ bias,
                              const float* __restrict__ Wl, const float* __restrict__ bl,
                              float* __restrict__ out, int n) {
    constexpr int CQ = 8;           // 32 channels / 4
    constexpr int NPB = BLK / CQ;   // 32 nodes per block
    __shared__ float4 Ws[64 * CQ];  // 8 KB: W[64][32] as quads
    __shared__ float4 Ag[NPB][CQ + 1];  // padded
    for (int i = threadIdx.x; i < 64 * CQ; i += BLK)
        Ws[i] = reinterpret_cast<const float4*>(W)[i];
    __syncthreads();
    const int cq = threadIdx.x % CQ;
    const int ns = threadIdx.x / CQ;
    const float4 bv = reinterpret_cast<const float4*>(bias)[cq];
    const float4 wlv = reinterpret_cast<const float4*>(Wl)[cq];
    const float blv = bl[0];
    const float4* P4 = reinterpret_cast<const float4*>(P);
    const ushort4* Pb4 = reinterpret_cast<const ushort4*>(Pb);
    const int node = blockIdx.x * NPB + ns;
    const int start = rowptr[node];
    const int deg = cnt[node];
    const float inv = 1.0f / (float)(deg + 1);
    const float4* pr = &P4[(size_t)node * CQ];

    float4 agg = {0.f, 0.f, 0.f, 0.f};
    int j = 0;
    for (; j + 7 < deg; j += 8) {
        const int s0 = adj[start + j];
        const int s1 = adj[start + j + 1];
        const int s2 = adj[start + j + 2];
        const int s3 = adj[start + j + 3];
        const int s4 = adj[start + j + 4];
        const int s5 = adj[start + j + 5];
        const int s6 = adj[start + j + 6];
        const int s7 = adj[start + j + 7];
        const ushort4 t0 = Pb4[(size_t)s0 * CQ + cq];
        const ushort4 t1 = Pb4[(size_t)s1 * CQ + cq];
        const ushort4 t2 = Pb4[(size_t)s2 * CQ + cq];
        const ushort4 t3 = Pb4[(size_t)s3 * CQ + cq];
        const ushort4 t4 = Pb4[(size_t)s4 * CQ + cq];
        const ushort4 t5 = Pb4[(size_t)s5 * CQ + cq];
        const ushort4 t6 = Pb4[(size_t)s6 * CQ + cq];
        const ushort4 t7 = Pb4[(size_t)s7 * CQ + cq];
        addbf4(agg, t0); addbf4(agg, t1); addbf4(agg, t2); addbf4(agg, t3);
        addbf4(agg, t4); addbf4(agg, t5); addbf4(agg, t6); addbf4(agg, t7);
    }
    if (j + 3 < deg) {
        const int s0 = adj[start + j];
        const int s1 = adj[start + j + 1];
        const int s2 = adj[start + j + 2];
        const int s3 = adj[start + j + 3];
        const ushort4 t0 = Pb4[(size_t)s0 * CQ + cq];
        const ushort4 t1 = Pb4[(size_t)s1 * CQ + cq];
        const ushort4 t2 = Pb4[(size_t)s2 * CQ + cq];
        const ushort4 t3 = Pb4[(size_t)s3 * CQ + cq];
        addbf4(agg, t0); addbf4(agg, t1); addbf4(agg, t2); addbf4(agg, t3);
        j += 4;
    }
    for (; j < deg; ++j)
        addbf4(agg, Pb4[(size_t)adj[start + j] * CQ + cq]);

    float4 acc = bv;
#pragma unroll
    for (int k4 = 0; k4 < 8; ++k4) {
        float4 pv = pr[k4];
        fma_step(acc, pv.x, Ws[(4 * k4 + 0) * CQ + cq]);
        fma_step(acc, pv.y, Ws[(4 * k4 + 1) * CQ + cq]);
        fma_step(acc, pv.z, Ws[(4 * k4 + 2) * CQ + cq]);
        fma_step(acc, pv.w, Ws[(4 * k4 + 3) * CQ + cq]);
    }
    {
        float4 pv = pr[cq];
        add4(agg, pv);
        agg.x *= inv; agg.y *= inv; agg.z *= inv; agg.w *= inv;
    }
    Ag[ns][cq] = agg;
    __syncthreads();
#pragma unroll
    for (int k4 = 0; k4 < 8; ++k4) {
        float4 av = Ag[ns][k4];
        fma_step(acc, av.x, Ws[(32 + 4 * k4 + 0) * CQ + cq]);
        fma_step(acc, av.y, Ws[(32 + 4 * k4 + 1) * CQ + cq]);
        fma_step(acc, av.z, Ws[(32 + 4 * k4 + 2) * CQ + cq]);
        fma_step(acc, av.w, Ws[(32 + 4 * k4 + 3) * CQ + cq]);
    }
    float v = fmaxf(acc.x, 0.0f) * wlv.x + fmaxf(acc.y, 0.0f) * wlv.y
            + fmaxf(acc.z, 0.0f) * wlv.z + fmaxf(acc.w, 0.0f) * wlv.w;
    v += __shfl_xor(v, 4, 8);
    v += __shfl_xor(v, 2, 8);
    v += __shfl_xor(v, 1, 8);
    if (cq == 0) out[node] = v + blv;
}

extern "C" void kernel_launch(void* const* d_in, const int* in_sizes, int n_in,
                              void* d_out, int out_size, void* d_ws, size_t ws_size,
                              hipStream_t stream) {
    const float* x    = (const float*)d_in[0];
    const int*   eraw = (const int*)d_in[1];
    const float* W2_1 = (const float*)d_in[2];
    const float* b2_1 = (const float*)d_in[3];
    const float* W1_1 = (const float*)d_in[4];
    const float* b1_1 = (const float*)d_in[5];
    const float* W2_2 = (const float*)d_in[6];
    const float* b2_2 = (const float*)d_in[7];
    const float* W1_2 = (const float*)d_in[8];
    const float* b1_2 = (const float*)d_in[9];
    const float* Wl   = (const float*)d_in[10];
    const float* bl   = (const float*)d_in[11];
    float* out = (float*)d_out;

    // workspace layout (~78 MB)
    char* ws = (char*)d_ws;
    int* flag   = (int*)ws;
    size_t off = 256;
    int* bhist  = (int*)(ws + off); off += sizeof(int) * (size_t)(NBKT + 2);
    off = (off + 255) & ~(size_t)255;
    int* base   = (int*)(ws + off); off += sizeof(int) * (size_t)(NBKT + 2);
    off = (off + 255) & ~(size_t)255;
    int* cursor = (int*)(ws + off); off += sizeof(int) * (size_t)(NBKT + 2);
    off = (off + 255) & ~(size_t)255;
    int* ebkt   = (int*)(ws + off); off += sizeof(int) * (size_t)N_EDGES;      // 6.4 MB
    off = (off + 255) & ~(size_t)255;
    int* adj    = (int*)(ws + off); off += sizeof(int) * (size_t)N_EDGES;      // 6.4 MB
    int* rowptr = (int*)(ws + off); off += sizeof(int) * (size_t)N_NODES;
    int* deg    = (int*)(ws + off); off += sizeof(int) * (size_t)N_NODES;
    off = (off + 255) & ~(size_t)255;
    float* bufA = (float*)(ws + off); off += sizeof(float) * (size_t)N_NODES * 64;  // 25.6 MB (h1pre fp32)
    unsigned short* bufAb = (unsigned short*)(ws + off);
    off += sizeof(unsigned short) * (size_t)N_NODES * 64;                           // 12.8 MB (h1pre bf16)
    off = (off + 255) & ~(size_t)255;
    float* bufC = (float*)(ws + off); off += sizeof(float) * (size_t)N_NODES * 32;  // 12.8 MB (h2pre fp32)
    unsigned short* bufCb = (unsigned short*)(ws + off);
    off += sizeof(unsigned short) * (size_t)N_NODES * 32;                           // 6.4 MB (h2pre bf16)

    hipMemsetAsync(bhist, 0, sizeof(int) * (size_t)(NBKT + 2), stream);

    detect_idx64<<<1, 64, 0, stream>>>((const unsigned int*)eraw, flag);
    bucket_hist<<<320, BLK, 0, stream>>>(eraw, flag, bhist);
    scan_buckets<<<1, 1024, 0, stream>>>(bhist, base, cursor);
    bucket_scatter<<<NSCAT, BLK, 0, stream>>>(eraw, flag, cursor, ebkt);
    csrify<<<NBKT, BLK, 0, stream>>>(base, ebkt, adj, rowptr, deg);

    // conv1 gemm (h1pre)
    gemm_bias<128, 64><<<N_NODES / 16, BLK, 0, stream>>>(x, W2_1, b2_1, bufA, bufAb, N_NODES);
    // conv1 update + conv2 lin2 fused (writes h2pre fp32+bf16 directly)
    update_gather_fused<64, 64, 1024><<<(N_NODES + 63) / 64, 1024, 0, stream>>>(
        bufA, bufAb, rowptr, deg, adj, W1_1, b1_1, W2_2, b2_2, bufC, bufCb, N_NODES);
    // conv2 update + final linear
    update2_final<<<N_NODES / 32, BLK, 0, stream>>>(bufC, bufCb, rowptr, deg, adj, W1_2, b1_2, Wl, bl, out, N_NODES);
}

// Round 15
// 191.672 us; speedup vs baseline: 1.1788x; 1.1788x over previous
//
#include <hip/hip_runtime.h>

#define N_NODES 100000
#define N_EDGES 1600000
constexpr int BLK = 256;
constexpr int NBKT = (N_NODES + 127) / 128;   // 782 buckets of 128 nodes
constexpr int BCAP = 4096;                    // padded bucket capacity (mean 2048, 45-sigma safe)
constexpr int PACK_SHIFT = 17;                // src < 2^17
constexpr int EPT = 16;                       // edges/thread in scatter
constexpr int EPBLK = BLK * EPT;              // 4096
constexpr int NSCAT = (N_EDGES + EPBLK - 1) / EPBLK;   // 391

// ---------- bf16 helpers (RTNE) ----------
__device__ __forceinline__ unsigned short f2bf(float f) {
    unsigned int u = __float_as_uint(f);
    u = (u + 0x7FFFu + ((u >> 16) & 1u)) >> 16;
    return (unsigned short)u;
}
__device__ __forceinline__ float bf2f(unsigned short s) {
    return __uint_as_float(((unsigned int)s) << 16);
}

// ---------- edge dtype detection (int32 vs int64-lowword) ----------
__global__ void detect_idx64(const unsigned int* __restrict__ e, int* __restrict__ flag) {
    if (blockIdx.x == 0 && threadIdx.x == 0) {
        int is64 = 1;
        for (int i = 0; i < 64; ++i) if (e[2 * i + 1] != 0u) { is64 = 0; break; }
        *flag = is64;
    }
}

__device__ __forceinline__ int load_dst(const int* e, int f, int i) {
    return f ? e[2 * (N_EDGES + i)] : e[N_EDGES + i];
}
__device__ __forceinline__ int load_src(const int* e, int f, int i) {
    return f ? e[2 * i] : e[i];
}

// ---------- single pass: block-aggregated scatter into PADDED bucket slots ----------
// cursor[b] starts at 0; bucket b's segment is ebkt[b*BCAP .. b*BCAP+cursor[b])
__global__ void bucket_scatter(const int* __restrict__ eraw, const int* __restrict__ flag,
                               int* __restrict__ cursor, int* __restrict__ ebkt) {
    __shared__ int h[NBKT];
    const int f = *flag;
    const int e0 = blockIdx.x * EPBLK;
    for (int i = threadIdx.x; i < NBKT; i += BLK) h[i] = 0;
    __syncthreads();
    int bs[EPT], ps[EPT];
#pragma unroll
    for (int k = 0; k < EPT; ++k) {
        const int i = e0 + k * BLK + threadIdx.x;
        if (i < N_EDGES) {
            const int d = load_dst(eraw, f, i);
            const int s = load_src(eraw, f, i);
            bs[k] = d >> 7;
            ps[k] = s | ((d & 127) << PACK_SHIFT);
            atomicAdd(&h[bs[k]], 1);
        } else {
            bs[k] = -1;
            ps[k] = 0;
        }
    }
    __syncthreads();
    // reserve within-bucket ranges; h[b] becomes this block's running offset
    for (int b = threadIdx.x; b < NBKT; b += BLK) {
        const int c = h[b];
        if (c) h[b] = atomicAdd(&cursor[b], c);
    }
    __syncthreads();
#pragma unroll
    for (int k = 0; k < EPT; ++k) {
        if (bs[k] >= 0) {
            const int off = atomicAdd(&h[bs[k]], 1);
            ebkt[bs[k] * BCAP + off] = ps[k];
        }
    }
}

// ---------- per-bucket CSR-ify (dense contiguous writes within padded segment) ----------
__global__ void csrify(const int* __restrict__ cnt_b, const int* __restrict__ ebkt,
                       int* __restrict__ adj, int* __restrict__ rowptr,
                       int* __restrict__ deg) {
    __shared__ int hist[128];
    __shared__ int excl[128];
    __shared__ int lcur[128];
    const int b = blockIdx.x;
    const int s0 = b * BCAP;
    const int s1 = s0 + cnt_b[b];
    for (int i = threadIdx.x; i < 128; i += BLK) hist[i] = 0;
    __syncthreads();
    for (int i = s0 + threadIdx.x; i < s1; i += BLK)
        atomicAdd(&hist[ebkt[i] >> PACK_SHIFT], 1);
    __syncthreads();
    if (threadIdx.x < 128) excl[threadIdx.x] = hist[threadIdx.x];
    __syncthreads();
    for (int off = 1; off < 128; off <<= 1) {
        int t = 0;
        if (threadIdx.x < 128 && threadIdx.x >= off) t = excl[threadIdx.x - off];
        __syncthreads();
        if (threadIdx.x < 128) excl[threadIdx.x] += t;
        __syncthreads();
    }
    if (threadIdx.x < 128) {
        const int e = excl[threadIdx.x] - hist[threadIdx.x];   // exclusive
        lcur[threadIdx.x] = s0 + e;
        const int node = b * 128 + threadIdx.x;
        if (node < N_NODES) {
            rowptr[node] = s0 + e;
            deg[node] = hist[threadIdx.x];
        }
    }
    __syncthreads();
    for (int i = s0 + threadIdx.x; i < s1; i += BLK) {
        const int p = ebkt[i];
        const int pos = atomicAdd(&lcur[p >> PACK_SHIFT], 1);
        adj[pos] = p & ((1 << PACK_SHIFT) - 1);
    }
}

// ---------- helpers ----------
__device__ __forceinline__ void fma_step(float4& acc, float xs, float4 w) {
    acc.x = fmaf(xs, w.x, acc.x);
    acc.y = fmaf(xs, w.y, acc.y);
    acc.z = fmaf(xs, w.z, acc.z);
    acc.w = fmaf(xs, w.w, acc.w);
}

__device__ __forceinline__ void add4(float4& a, float4 v) {
    a.x += v.x; a.y += v.y; a.z += v.z; a.w += v.w;
}

__device__ __forceinline__ void addbf4(float4& a, ushort4 t) {
    a.x += bf2f(t.x); a.y += bf2f(t.y); a.z += bf2f(t.z); a.w += bf2f(t.w);
}

// ---------- Y[n,C] = X[n,K] @ W[K,C] + b, x LDS-staged; also writes bf16 copy ----------
template<int K, int C>
__global__ void gemm_bias(const float* __restrict__ X, const float* __restrict__ W,
                          const float* __restrict__ bias, float* __restrict__ Y,
                          unsigned short* __restrict__ Yb, int n) {
    constexpr int CQ = C / 4;
    constexpr int NPB = BLK / CQ;
    constexpr int KQ = K / 4;
    __shared__ float4 Ws[K * CQ];
    __shared__ float4 xL[NPB * KQ];
    for (int i = threadIdx.x; i < K * CQ; i += BLK)
        Ws[i] = reinterpret_cast<const float4*>(W)[i];
    const int cq = threadIdx.x % CQ;
    const int ns = threadIdx.x / CQ;
    const float4 bv = reinterpret_cast<const float4*>(bias)[cq];
    const float4* X4 = reinterpret_cast<const float4*>(X);
    const int tile = blockIdx.x;
    for (int i = threadIdx.x; i < NPB * KQ; i += BLK) {
        const int r = i / KQ;
        const int k4 = i % KQ;
        xL[r * KQ + ((k4 + r) % KQ)] = X4[(size_t)(tile * NPB + r) * KQ + k4];
    }
    __syncthreads();
    const float4* xr = &xL[ns * KQ];
    float4 acc = bv;
#pragma unroll 4
    for (int k4 = 0; k4 < KQ; ++k4) {
        float4 xv = xr[(k4 + ns) % KQ];
        fma_step(acc, xv.x, Ws[(4 * k4 + 0) * CQ + cq]);
        fma_step(acc, xv.y, Ws[(4 * k4 + 1) * CQ + cq]);
        fma_step(acc, xv.z, Ws[(4 * k4 + 2) * CQ + cq]);
        fma_step(acc, xv.w, Ws[(4 * k4 + 3) * CQ + cq]);
    }
    const size_t oi = (size_t)(tile * NPB + ns) * CQ + cq;
    reinterpret_cast<float4*>(Y)[oi] = acc;
    ushort4 bfv;
    bfv.x = f2bf(acc.x); bfv.y = f2bf(acc.y);
    bfv.z = f2bf(acc.z); bfv.w = f2bf(acc.w);
    reinterpret_cast<ushort4*>(Yb)[oi] = bfv;
}

// ---------- fused gather-aggregate + update: Y = relu(concat(P, agg) @ W + b) ----------
// TPB=512, NPB=32 (r12 best); unroll-8 bf16 gather
template<int KH, int C, int TPB>
__global__ void update_gather(const float* __restrict__ P,
                              const unsigned short* __restrict__ Pb,
                              const int* __restrict__ rowptr, const int* __restrict__ cnt,
                              const int* __restrict__ adj,
                              const float* __restrict__ W, const float* __restrict__ bias,
                              float* __restrict__ Y, int n) {
    constexpr int CQ = C / 4;
    constexpr int NPB = TPB / CQ;
    constexpr int K = 2 * KH;
    __shared__ float4 Ws[K * CQ];
    __shared__ float4 Ag[NPB][CQ + 1];
    for (int i = threadIdx.x; i < K * CQ; i += TPB)
        Ws[i] = reinterpret_cast<const float4*>(W)[i];
    __syncthreads();
    const int cq = threadIdx.x % CQ;
    const int ns = threadIdx.x / CQ;
    const float4 bv = reinterpret_cast<const float4*>(bias)[cq];
    const float4* P4 = reinterpret_cast<const float4*>(P);
    const ushort4* Pb4 = reinterpret_cast<const ushort4*>(Pb);
    const int node = blockIdx.x * NPB + ns;
    const int start = rowptr[node];
    const int deg = cnt[node];
    const float inv = 1.0f / (float)(deg + 1);
    const float4* pr = &P4[(size_t)node * CQ];

    float4 agg = {0.f, 0.f, 0.f, 0.f};
    int j = 0;
    for (; j + 7 < deg; j += 8) {
        const int s0 = adj[start + j];
        const int s1 = adj[start + j + 1];
        const int s2 = adj[start + j + 2];
        const int s3 = adj[start + j + 3];
        const int s4 = adj[start + j + 4];
        const int s5 = adj[start + j + 5];
        const int s6 = adj[start + j + 6];
        const int s7 = adj[start + j + 7];
        const ushort4 t0 = Pb4[(size_t)s0 * CQ + cq];
        const ushort4 t1 = Pb4[(size_t)s1 * CQ + cq];
        const ushort4 t2 = Pb4[(size_t)s2 * CQ + cq];
        const ushort4 t3 = Pb4[(size_t)s3 * CQ + cq];
        const ushort4 t4 = Pb4[(size_t)s4 * CQ + cq];
        const ushort4 t5 = Pb4[(size_t)s5 * CQ + cq];
        const ushort4 t6 = Pb4[(size_t)s6 * CQ + cq];
        const ushort4 t7 = Pb4[(size_t)s7 * CQ + cq];
        addbf4(agg, t0); addbf4(agg, t1); addbf4(agg, t2); addbf4(agg, t3);
        addbf4(agg, t4); addbf4(agg, t5); addbf4(agg, t6); addbf4(agg, t7);
    }
    if (j + 3 < deg) {
        const int s0 = adj[start + j];
        const int s1 = adj[start + j + 1];
        const int s2 = adj[start + j + 2];
        const int s3 = adj[start + j + 3];
        const ushort4 t0 = Pb4[(size_t)s0 * CQ + cq];
        const ushort4 t1 = Pb4[(size_t)s1 * CQ + cq];
        const ushort4 t2 = Pb4[(size_t)s2 * CQ + cq];
        const ushort4 t3 = Pb4[(size_t)s3 * CQ + cq];
        addbf4(agg, t0); addbf4(agg, t1); addbf4(agg, t2); addbf4(agg, t3);
        j += 4;
    }
    for (; j < deg; ++j)
        addbf4(agg, Pb4[(size_t)adj[start + j] * CQ + cq]);

    float4 acc = bv;
#pragma unroll 4
    for (int k4 = 0; k4 < KH / 4; ++k4) {
        float4 pv = pr[k4];
        fma_step(acc, pv.x, Ws[(4 * k4 + 0) * CQ + cq]);
        fma_step(acc, pv.y, Ws[(4 * k4 + 1) * CQ + cq]);
        fma_step(acc, pv.z, Ws[(4 * k4 + 2) * CQ + cq]);
        fma_step(acc, pv.w, Ws[(4 * k4 + 3) * CQ + cq]);
    }
    {
        float4 pv = pr[cq];
        add4(agg, pv);
        agg.x *= inv; agg.y *= inv; agg.z *= inv; agg.w *= inv;
    }
    Ag[ns][cq] = agg;
    __syncthreads();
#pragma unroll 4
    for (int k4 = 0; k4 < KH / 4; ++k4) {
        float4 av = Ag[ns][k4];
        fma_step(acc, av.x, Ws[(KH + 4 * k4 + 0) * CQ + cq]);
        fma_step(acc, av.y, Ws[(KH + 4 * k4 + 1) * CQ + cq]);
        fma_step(acc, av.z, Ws[(KH + 4 * k4 + 2) * CQ + cq]);
        fma_step(acc, av.w, Ws[(KH + 4 * k4 + 3) * CQ + cq]);
    }
    acc.x = fmaxf(acc.x, 0.0f);
    acc.y = fmaxf(acc.y, 0.0f);
    acc.z = fmaxf(acc.z, 0.0f);
    acc.w = fmaxf(acc.w, 0.0f);
    reinterpret_cast<float4*>(Y)[(size_t)node * CQ + cq] = acc;
}

// ---------- conv2 update (bf16 ushort4 gather) fused with final 32->1 linear ----------
__global__ void update2_final(const float* __restrict__ P,
                              const unsigned short* __restrict__ Pb,
                              const int* __restrict__ rowptr, const int* __restrict__ cnt,
                              const int* __restrict__ adj,
                              const float* __restrict__ W, const float* __restrict__ bias,
                              const float* __restrict__ Wl, const float* __restrict__ bl,
                              float* __restrict__ out, int n) {
    constexpr int CQ = 8;
    constexpr int NPB = BLK / CQ;
    __shared__ float4 Ws[64 * CQ];
    __shared__ float4 Ag[NPB][CQ + 1];
    for (int i = threadIdx.x; i < 64 * CQ; i += BLK)
        Ws[i] = reinterpret_cast<const float4*>(W)[i];
    __syncthreads();
    const int cq = threadIdx.x % CQ;
    const int ns = threadIdx.x / CQ;
    const float4 bv = reinterpret_cast<const float4*>(bias)[cq];
    const float4 wlv = reinterpret_cast<const float4*>(Wl)[cq];
    const float blv = bl[0];
    const float4* P4 = reinterpret_cast<const float4*>(P);
    const ushort4* Pb4 = reinterpret_cast<const ushort4*>(Pb);
    const int node = blockIdx.x * NPB + ns;
    const int start = rowptr[node];
    const int deg = cnt[node];
    const float inv = 1.0f / (float)(deg + 1);
    const float4* pr = &P4[(size_t)node * CQ];

    float4 agg = {0.f, 0.f, 0.f, 0.f};
    int j = 0;
    for (; j + 7 < deg; j += 8) {
        const int s0 = adj[start + j];
        const int s1 = adj[start + j + 1];
        const int s2 = adj[start + j + 2];
        const int s3 = adj[start + j + 3];
        const int s4 = adj[start + j + 4];
        const int s5 = adj[start + j + 5];
        const int s6 = adj[start + j + 6];
        const int s7 = adj[start + j + 7];
        const ushort4 t0 = Pb4[(size_t)s0 * CQ + cq];
        const ushort4 t1 = Pb4[(size_t)s1 * CQ + cq];
        const ushort4 t2 = Pb4[(size_t)s2 * CQ + cq];
        const ushort4 t3 = Pb4[(size_t)s3 * CQ + cq];
        const ushort4 t4 = Pb4[(size_t)s4 * CQ + cq];
        const ushort4 t5 = Pb4[(size_t)s5 * CQ + cq];
        const ushort4 t6 = Pb4[(size_t)s6 * CQ + cq];
        const ushort4 t7 = Pb4[(size_t)s7 * CQ + cq];
        addbf4(agg, t0); addbf4(agg, t1); addbf4(agg, t2); addbf4(agg, t3);
        addbf4(agg, t4); addbf4(agg, t5); addbf4(agg, t6); addbf4(agg, t7);
    }
    if (j + 3 < deg) {
        const int s0 = adj[start + j];
        const int s1 = adj[start + j + 1];
        const int s2 = adj[start + j + 2];
        const int s3 = adj[start + j + 3];
        const ushort4 t0 = Pb4[(size_t)s0 * CQ + cq];
        const ushort4 t1 = Pb4[(size_t)s1 * CQ + cq];
        const ushort4 t2 = Pb4[(size_t)s2 * CQ + cq];
        const ushort4 t3 = Pb4[(size_t)s3 * CQ + cq];
        addbf4(agg, t0); addbf4(agg, t1); addbf4(agg, t2); addbf4(agg, t3);
        j += 4;
    }
    for (; j < deg; ++j)
        addbf4(agg, Pb4[(size_t)adj[start + j] * CQ + cq]);

    float4 acc = bv;
#pragma unroll
    for (int k4 = 0; k4 < 8; ++k4) {
        float4 pv = pr[k4];
        fma_step(acc, pv.x, Ws[(4 * k4 + 0) * CQ + cq]);
        fma_step(acc, pv.y, Ws[(4 * k4 + 1) * CQ + cq]);
        fma_step(acc, pv.z, Ws[(4 * k4 + 2) * CQ + cq]);
        fma_step(acc, pv.w, Ws[(4 * k4 + 3) * CQ + cq]);
    }
    {
        float4 pv = pr[cq];
        add4(agg, pv);
        agg.x *= inv; agg.y *= inv; agg.z *= inv; agg.w *= inv;
    }
    Ag[ns][cq] = agg;
    __syncthreads();
#pragma unroll
    for (int k4 = 0; k4 < 8; ++k4) {
        float4 av = Ag[ns][k4];
        fma_step(acc, av.x, Ws[(32 + 4 * k4 + 0) * CQ + cq]);
        fma_step(acc, av.y, Ws[(32 + 4 * k4 + 1) * CQ + cq]);
        fma_step(acc, av.z, Ws[(32 + 4 * k4 + 2) * CQ + cq]);
        fma_step(acc, av.w, Ws[(32 + 4 * k4 + 3) * CQ + cq]);
    }
    float v = fmaxf(acc.x, 0.0f) * wlv.x + fmaxf(acc.y, 0.0f) * wlv.y
            + fmaxf(acc.z, 0.0f) * wlv.z + fmaxf(acc.w, 0.0f) * wlv.w;
    v += __shfl_xor(v, 4, 8);
    v += __shfl_xor(v, 2, 8);
    v += __shfl_xor(v, 1, 8);
    if (cq == 0) out[node] = v + blv;
}

extern "C" void kernel_launch(void* const* d_in, const int* in_sizes, int n_in,
                              void* d_out, int out_size, void* d_ws, size_t ws_size,
                              hipStream_t stream) {
    const float* x    = (const float*)d_in[0];
    const int*   eraw = (const int*)d_in[1];
    const float* W2_1 = (const float*)d_in[2];
    const float* b2_1 = (const float*)d_in[3];
    const float* W1_1 = (const float*)d_in[4];
    const float* b1_1 = (const float*)d_in[5];
    const float* W2_2 = (const float*)d_in[6];
    const float* b2_2 = (const float*)d_in[7];
    const float* W1_2 = (const float*)d_in[8];
    const float* b1_2 = (const float*)d_in[9];
    const float* Wl   = (const float*)d_in[10];
    const float* bl   = (const float*)d_in[11];
    float* out = (float*)d_out;

    // workspace layout (~97 MB)
    char* ws = (char*)d_ws;
    int* flag   = (int*)ws;
    size_t off = 256;
    int* cursor = (int*)(ws + off); off += sizeof(int) * (size_t)(NBKT + 2);
    off = (off + 255) & ~(size_t)255;
    int* ebkt   = (int*)(ws + off); off += sizeof(int) * (size_t)NBKT * BCAP;  // 12.8 MB (padded)
    off = (off + 255) & ~(size_t)255;
    int* adj    = (int*)(ws + off); off += sizeof(int) * (size_t)NBKT * BCAP;  // 12.8 MB (padded)
    int* rowptr = (int*)(ws + off); off += sizeof(int) * (size_t)N_NODES;
    int* deg    = (int*)(ws + off); off += sizeof(int) * (size_t)N_NODES;
    off = (off + 255) & ~(size_t)255;
    float* bufA = (float*)(ws + off); off += sizeof(float) * (size_t)N_NODES * 64;  // 25.6 MB
    float* bufC = (float*)(ws + off); off += sizeof(float) * (size_t)N_NODES * 64;  // 25.6 MB
    unsigned short* bufAb = (unsigned short*)(ws + off);
    off += sizeof(unsigned short) * (size_t)N_NODES * 64;                           // 12.8 MB

    hipMemsetAsync(cursor, 0, sizeof(int) * (size_t)(NBKT + 2), stream);

    detect_idx64<<<1, 64, 0, stream>>>((const unsigned int*)eraw, flag);
    bucket_scatter<<<NSCAT, BLK, 0, stream>>>(eraw, flag, cursor, ebkt);
    csrify<<<NBKT, BLK, 0, stream>>>(cursor, ebkt, adj, rowptr, deg);

    // conv1
    gemm_bias<128, 64><<<N_NODES / 16, BLK, 0, stream>>>(x, W2_1, b2_1, bufA, bufAb, N_NODES);
    update_gather<64, 64, 512><<<N_NODES / 32, 512, 0, stream>>>(bufA, bufAb, rowptr, deg, adj, W1_1, b1_1, bufC, N_NODES);

    // conv2 (reuse bufA fp32 + bufAb bf16 for h2pre)
    gemm_bias<64, 32><<<N_NODES / 32, BLK, 0, stream>>>(bufC, W2_2, b2_2, bufA, bufAb, N_NODES);
    update2_final<<<N_NODES / 32, BLK, 0, stream>>>(bufA, bufAb, rowptr, deg, adj, W1_2, b1_2, Wl, bl, out, N_NODES);
}

// Round 16
// 186.977 us; speedup vs baseline: 1.2084x; 1.0251x over previous
//
#include <hip/hip_runtime.h>

#define N_NODES 100000
#define N_EDGES 1600000
constexpr int BLK = 256;
constexpr int NBKT = (N_NODES + 127) / 128;   // 782 buckets of 128 nodes
constexpr int BCAP = 4096;                    // padded bucket capacity
constexpr int PACK_SHIFT = 17;                // src < 2^17
constexpr int EPT = 16;                       // edges/thread in scatter
constexpr int EPBLK = BLK * EPT;              // 4096
constexpr int NSCAT = (N_EDGES + EPBLK - 1) / EPBLK;   // 391
constexpr int GTILES = N_NODES / 16;          // 6250 gemm<128,64> tiles
constexpr int GHALF = GTILES / 2;             // 3125

// ---------- bf16 helpers (RTNE) ----------
__device__ __forceinline__ unsigned short f2bf(float f) {
    unsigned int u = __float_as_uint(f);
    u = (u + 0x7FFFu + ((u >> 16) & 1u)) >> 16;
    return (unsigned short)u;
}
__device__ __forceinline__ float bf2f(unsigned short s) {
    return __uint_as_float(((unsigned int)s) << 16);
}

// ---------- edge dtype detection (int32 vs int64-lowword) ----------
__global__ void detect_idx64(const unsigned int* __restrict__ e, int* __restrict__ flag) {
    if (blockIdx.x == 0 && threadIdx.x == 0) {
        int is64 = 1;
        for (int i = 0; i < 64; ++i) if (e[2 * i + 1] != 0u) { is64 = 0; break; }
        *flag = is64;
    }
}

__device__ __forceinline__ int load_dst(const int* e, int f, int i) {
    return f ? e[2 * (N_EDGES + i)] : e[N_EDGES + i];
}
__device__ __forceinline__ int load_src(const int* e, int f, int i) {
    return f ? e[2 * i] : e[i];
}

// ---------- helpers ----------
__device__ __forceinline__ void fma_step(float4& acc, float xs, float4 w) {
    acc.x = fmaf(xs, w.x, acc.x);
    acc.y = fmaf(xs, w.y, acc.y);
    acc.z = fmaf(xs, w.z, acc.z);
    acc.w = fmaf(xs, w.w, acc.w);
}
__device__ __forceinline__ void add4(float4& a, float4 v) {
    a.x += v.x; a.y += v.y; a.z += v.z; a.w += v.w;
}
__device__ __forceinline__ void addbf4(float4& a, ushort4 t) {
    a.x += bf2f(t.x); a.y += bf2f(t.y); a.z += bf2f(t.z); a.w += bf2f(t.w);
}

// ---------- device bodies sharing an LDS union ----------

// scatter: block-aggregated scatter into PADDED bucket slots (uses 3128B of smem)
__device__ void scatter_body(const int* __restrict__ eraw, int f,
                             int* __restrict__ cursor, int* __restrict__ ebkt,
                             int bid, void* smem) {
    int* h = (int*)smem;
    const int e0 = bid * EPBLK;
    for (int i = threadIdx.x; i < NBKT; i += BLK) h[i] = 0;
    __syncthreads();
    int bs[EPT], ps[EPT];
#pragma unroll
    for (int k = 0; k < EPT; ++k) {
        const int i = e0 + k * BLK + threadIdx.x;
        if (i < N_EDGES) {
            const int d = load_dst(eraw, f, i);
            const int s = load_src(eraw, f, i);
            bs[k] = d >> 7;
            ps[k] = s | ((d & 127) << PACK_SHIFT);
            atomicAdd(&h[bs[k]], 1);
        } else {
            bs[k] = -1;
            ps[k] = 0;
        }
    }
    __syncthreads();
    for (int b = threadIdx.x; b < NBKT; b += BLK) {
        const int c = h[b];
        if (c) h[b] = atomicAdd(&cursor[b], c);
    }
    __syncthreads();
#pragma unroll
    for (int k = 0; k < EPT; ++k) {
        if (bs[k] >= 0) {
            const int off = atomicAdd(&h[bs[k]], 1);
            ebkt[bs[k] * BCAP + off] = ps[k];
        }
    }
}

// csrify: per-bucket reorder into per-node CSR (uses 1536B of smem)
__device__ void csrify_body(const int* __restrict__ cnt_b, const int* __restrict__ ebkt,
                            int* __restrict__ adj, int* __restrict__ rowptr,
                            int* __restrict__ deg, int b, void* smem) {
    int* hist = (int*)smem;
    int* excl = hist + 128;
    int* lcur = hist + 256;
    const int s0 = b * BCAP;
    const int s1 = s0 + cnt_b[b];
    for (int i = threadIdx.x; i < 128; i += BLK) hist[i] = 0;
    __syncthreads();
    for (int i = s0 + threadIdx.x; i < s1; i += BLK)
        atomicAdd(&hist[ebkt[i] >> PACK_SHIFT], 1);
    __syncthreads();
    if (threadIdx.x < 128) excl[threadIdx.x] = hist[threadIdx.x];
    __syncthreads();
    for (int off = 1; off < 128; off <<= 1) {
        int t = 0;
        if (threadIdx.x < 128 && threadIdx.x >= off) t = excl[threadIdx.x - off];
        __syncthreads();
        if (threadIdx.x < 128) excl[threadIdx.x] += t;
        __syncthreads();
    }
    if (threadIdx.x < 128) {
        const int e = excl[threadIdx.x] - hist[threadIdx.x];
        lcur[threadIdx.x] = s0 + e;
        const int node = b * 128 + threadIdx.x;
        if (node < N_NODES) {
            rowptr[node] = s0 + e;
            deg[node] = hist[threadIdx.x];
        }
    }
    __syncthreads();
    for (int i = s0 + threadIdx.x; i < s1; i += BLK) {
        const int p = ebkt[i];
        const int pos = atomicAdd(&lcur[p >> PACK_SHIFT], 1);
        adj[pos] = p & ((1 << PACK_SHIFT) - 1);
    }
}

// gemm tile body (uses 40960B of smem for K=128,C=64)
template<int K, int C>
__device__ void gemm_body(const float* __restrict__ X, const float* __restrict__ W,
                          const float* __restrict__ bias, float* __restrict__ Y,
                          unsigned short* __restrict__ Yb, int tile, void* smem) {
    constexpr int CQ = C / 4;
    constexpr int NPB = BLK / CQ;
    constexpr int KQ = K / 4;
    float4* Ws = (float4*)smem;            // K*CQ
    float4* xL = Ws + K * CQ;              // NPB*KQ
    for (int i = threadIdx.x; i < K * CQ; i += BLK)
        Ws[i] = reinterpret_cast<const float4*>(W)[i];
    const int cq = threadIdx.x % CQ;
    const int ns = threadIdx.x / CQ;
    const float4 bv = reinterpret_cast<const float4*>(bias)[cq];
    const float4* X4 = reinterpret_cast<const float4*>(X);
    for (int i = threadIdx.x; i < NPB * KQ; i += BLK) {
        const int r = i / KQ;
        const int k4 = i % KQ;
        xL[r * KQ + ((k4 + r) % KQ)] = X4[(size_t)(tile * NPB + r) * KQ + k4];
    }
    __syncthreads();
    const float4* xr = &xL[ns * KQ];
    float4 acc = bv;
#pragma unroll 4
    for (int k4 = 0; k4 < KQ; ++k4) {
        float4 xv = xr[(k4 + ns) % KQ];
        fma_step(acc, xv.x, Ws[(4 * k4 + 0) * CQ + cq]);
        fma_step(acc, xv.y, Ws[(4 * k4 + 1) * CQ + cq]);
        fma_step(acc, xv.z, Ws[(4 * k4 + 2) * CQ + cq]);
        fma_step(acc, xv.w, Ws[(4 * k4 + 3) * CQ + cq]);
    }
    const size_t oi = (size_t)(tile * NPB + ns) * CQ + cq;
    reinterpret_cast<float4*>(Y)[oi] = acc;
    ushort4 bfv;
    bfv.x = f2bf(acc.x); bfv.y = f2bf(acc.y);
    bfv.z = f2bf(acc.z); bfv.w = f2bf(acc.w);
    reinterpret_cast<ushort4*>(Yb)[oi] = bfv;
}

// ---------- fat kernel A: scatter blocks + gemm tiles [0, GHALF) ----------
__global__ void scatter_gemm(const int* __restrict__ eraw, const int* __restrict__ flag,
                             int* __restrict__ cursor, int* __restrict__ ebkt,
                             const float* __restrict__ X, const float* __restrict__ W,
                             const float* __restrict__ bias, float* __restrict__ Y,
                             unsigned short* __restrict__ Yb) {
    __shared__ float4 smem[2560];   // 40960 B union
    if (blockIdx.x < NSCAT) {
        scatter_body(eraw, *flag, cursor, ebkt, blockIdx.x, smem);
    } else {
        gemm_body<128, 64>(X, W, bias, Y, Yb, blockIdx.x - NSCAT, smem);
    }
}

// ---------- fat kernel B: csrify blocks + gemm tiles [GHALF, GTILES) ----------
__global__ void csrify_gemm(const int* __restrict__ cnt_b, const int* __restrict__ ebkt,
                            int* __restrict__ adj, int* __restrict__ rowptr,
                            int* __restrict__ deg,
                            const float* __restrict__ X, const float* __restrict__ W,
                            const float* __restrict__ bias, float* __restrict__ Y,
                            unsigned short* __restrict__ Yb) {
    __shared__ float4 smem[2560];
    if (blockIdx.x < NBKT) {
        csrify_body(cnt_b, ebkt, adj, rowptr, deg, blockIdx.x, smem);
    } else {
        gemm_body<128, 64>(X, W, bias, Y, Yb, GHALF + (int)blockIdx.x - NBKT, smem);
    }
}

// ---------- standalone gemm (conv2 lin2) ----------
template<int K, int C>
__global__ void gemm_bias(const float* __restrict__ X, const float* __restrict__ W,
                          const float* __restrict__ bias, float* __restrict__ Y,
                          unsigned short* __restrict__ Yb, int n) {
    constexpr int CQ = C / 4;
    constexpr int NPB = BLK / CQ;
    constexpr int KQ = K / 4;
    __shared__ float4 Ws[K * CQ];
    __shared__ float4 xL[NPB * KQ];
    for (int i = threadIdx.x; i < K * CQ; i += BLK)
        Ws[i] = reinterpret_cast<const float4*>(W)[i];
    const int cq = threadIdx.x % CQ;
    const int ns = threadIdx.x / CQ;
    const float4 bv = reinterpret_cast<const float4*>(bias)[cq];
    const float4* X4 = reinterpret_cast<const float4*>(X);
    const int tile = blockIdx.x;
    for (int i = threadIdx.x; i < NPB * KQ; i += BLK) {
        const int r = i / KQ;
        const int k4 = i % KQ;
        xL[r * KQ + ((k4 + r) % KQ)] = X4[(size_t)(tile * NPB + r) * KQ + k4];
    }
    __syncthreads();
    const float4* xr = &xL[ns * KQ];
    float4 acc = bv;
#pragma unroll 4
    for (int k4 = 0; k4 < KQ; ++k4) {
        float4 xv = xr[(k4 + ns) % KQ];
        fma_step(acc, xv.x, Ws[(4 * k4 + 0) * CQ + cq]);
        fma_step(acc, xv.y, Ws[(4 * k4 + 1) * CQ + cq]);
        fma_step(acc, xv.z, Ws[(4 * k4 + 2) * CQ + cq]);
        fma_step(acc, xv.w, Ws[(4 * k4 + 3) * CQ + cq]);
    }
    const size_t oi = (size_t)(tile * NPB + ns) * CQ + cq;
    reinterpret_cast<float4*>(Y)[oi] = acc;
    ushort4 bfv;
    bfv.x = f2bf(acc.x); bfv.y = f2bf(acc.y);
    bfv.z = f2bf(acc.z); bfv.w = f2bf(acc.w);
    reinterpret_cast<ushort4*>(Yb)[oi] = bfv;
}

// ---------- fused gather-aggregate + update: Y = relu(concat(P, agg) @ W + b) ----------
template<int KH, int C, int TPB>
__global__ void update_gather(const float* __restrict__ P,
                              const unsigned short* __restrict__ Pb,
                              const int* __restrict__ rowptr, const int* __restrict__ cnt,
                              const int* __restrict__ adj,
                              const float* __restrict__ W, const float* __restrict__ bias,
                              float* __restrict__ Y, int n) {
    constexpr int CQ = C / 4;
    constexpr int NPB = TPB / CQ;
    constexpr int K = 2 * KH;
    __shared__ float4 Ws[K * CQ];
    __shared__ float4 Ag[NPB][CQ + 1];
    for (int i = threadIdx.x; i < K * CQ; i += TPB)
        Ws[i] = reinterpret_cast<const float4*>(W)[i];
    __syncthreads();
    const int cq = threadIdx.x % CQ;
    const int ns = threadIdx.x / CQ;
    const float4 bv = reinterpret_cast<const float4*>(bias)[cq];
    const float4* P4 = reinterpret_cast<const float4*>(P);
    const ushort4* Pb4 = reinterpret_cast<const ushort4*>(Pb);
    const int node = blockIdx.x * NPB + ns;
    const int start = rowptr[node];
    const int deg = cnt[node];
    const float inv = 1.0f / (float)(deg + 1);
    const float4* pr = &P4[(size_t)node * CQ];

    float4 agg = {0.f, 0.f, 0.f, 0.f};
    int j = 0;
    for (; j + 7 < deg; j += 8) {
        const int s0 = adj[start + j];
        const int s1 = adj[start + j + 1];
        const int s2 = adj[start + j + 2];
        const int s3 = adj[start + j + 3];
        const int s4 = adj[start + j + 4];
        const int s5 = adj[start + j + 5];
        const int s6 = adj[start + j + 6];
        const int s7 = adj[start + j + 7];
        const ushort4 t0 = Pb4[(size_t)s0 * CQ + cq];
        const ushort4 t1 = Pb4[(size_t)s1 * CQ + cq];
        const ushort4 t2 = Pb4[(size_t)s2 * CQ + cq];
        const ushort4 t3 = Pb4[(size_t)s3 * CQ + cq];
        const ushort4 t4 = Pb4[(size_t)s4 * CQ + cq];
        const ushort4 t5 = Pb4[(size_t)s5 * CQ + cq];
        const ushort4 t6 = Pb4[(size_t)s6 * CQ + cq];
        const ushort4 t7 = Pb4[(size_t)s7 * CQ + cq];
        addbf4(agg, t0); addbf4(agg, t1); addbf4(agg, t2); addbf4(agg, t3);
        addbf4(agg, t4); addbf4(agg, t5); addbf4(agg, t6); addbf4(agg, t7);
    }
    if (j + 3 < deg) {
        const int s0 = adj[start + j];
        const int s1 = adj[start + j + 1];
        const int s2 = adj[start + j + 2];
        const int s3 = adj[start + j + 3];
        const ushort4 t0 = Pb4[(size_t)s0 * CQ + cq];
        const ushort4 t1 = Pb4[(size_t)s1 * CQ + cq];
        const ushort4 t2 = Pb4[(size_t)s2 * CQ + cq];
        const ushort4 t3 = Pb4[(size_t)s3 * CQ + cq];
        addbf4(agg, t0); addbf4(agg, t1); addbf4(agg, t2); addbf4(agg, t3);
        j += 4;
    }
    for (; j < deg; ++j)
        addbf4(agg, Pb4[(size_t)adj[start + j] * CQ + cq]);

    float4 acc = bv;
#pragma unroll 4
    for (int k4 = 0; k4 < KH / 4; ++k4) {
        float4 pv = pr[k4];
        fma_step(acc, pv.x, Ws[(4 * k4 + 0) * CQ + cq]);
        fma_step(acc, pv.y, Ws[(4 * k4 + 1) * CQ + cq]);
        fma_step(acc, pv.z, Ws[(4 * k4 + 2) * CQ + cq]);
        fma_step(acc, pv.w, Ws[(4 * k4 + 3) * CQ + cq]);
    }
    {
        float4 pv = pr[cq];
        add4(agg, pv);
        agg.x *= inv; agg.y *= inv; agg.z *= inv; agg.w *= inv;
    }
    Ag[ns][cq] = agg;
    __syncthreads();
#pragma unroll 4
    for (int k4 = 0; k4 < KH / 4; ++k4) {
        float4 av = Ag[ns][k4];
        fma_step(acc, av.x, Ws[(KH + 4 * k4 + 0) * CQ + cq]);
        fma_step(acc, av.y, Ws[(KH + 4 * k4 + 1) * CQ + cq]);
        fma_step(acc, av.z, Ws[(KH + 4 * k4 + 2) * CQ + cq]);
        fma_step(acc, av.w, Ws[(KH + 4 * k4 + 3) * CQ + cq]);
    }
    acc.x = fmaxf(acc.x, 0.0f);
    acc.y = fmaxf(acc.y, 0.0f);
    acc.z = fmaxf(acc.z, 0.0f);
    acc.w = fmaxf(acc.w, 0.0f);
    reinterpret_cast<float4*>(Y)[(size_t)node * CQ + cq] = acc;
}

// ---------- conv2 update (bf16 ushort4 gather) fused with final 32->1 linear ----------
__global__ void update2_final(const float* __restrict__ P,
                              const unsigned short* __restrict__ Pb,
                              const int* __restrict__ rowptr, const int* __restrict__ cnt,
                              const int* __restrict__ adj,
                              const float* __restrict__ W, const float* __restrict__ bias,
                              const float* __restrict__ Wl, const float* __restrict__ bl,
                              float* __restrict__ out, int n) {
    constexpr int CQ = 8;
    constexpr int NPB = BLK / CQ;
    __shared__ float4 Ws[64 * CQ];
    __shared__ float4 Ag[NPB][CQ + 1];
    for (int i = threadIdx.x; i < 64 * CQ; i += BLK)
        Ws[i] = reinterpret_cast<const float4*>(W)[i];
    __syncthreads();
    const int cq = threadIdx.x % CQ;
    const int ns = threadIdx.x / CQ;
    const float4 bv = reinterpret_cast<const float4*>(bias)[cq];
    const float4 wlv = reinterpret_cast<const float4*>(Wl)[cq];
    const float blv = bl[0];
    const float4* P4 = reinterpret_cast<const float4*>(P);
    const ushort4* Pb4 = reinterpret_cast<const ushort4*>(Pb);
    const int node = blockIdx.x * NPB + ns;
    const int start = rowptr[node];
    const int deg = cnt[node];
    const float inv = 1.0f / (float)(deg + 1);
    const float4* pr = &P4[(size_t)node * CQ];

    float4 agg = {0.f, 0.f, 0.f, 0.f};
    int j = 0;
    for (; j + 7 < deg; j += 8) {
        const int s0 = adj[start + j];
        const int s1 = adj[start + j + 1];
        const int s2 = adj[start + j + 2];
        const int s3 = adj[start + j + 3];
        const int s4 = adj[start + j + 4];
        const int s5 = adj[start + j + 5];
        const int s6 = adj[start + j + 6];
        const int s7 = adj[start + j + 7];
        const ushort4 t0 = Pb4[(size_t)s0 * CQ + cq];
        const ushort4 t1 = Pb4[(size_t)s1 * CQ + cq];
        const ushort4 t2 = Pb4[(size_t)s2 * CQ + cq];
        const ushort4 t3 = Pb4[(size_t)s3 * CQ + cq];
        const ushort4 t4 = Pb4[(size_t)s4 * CQ + cq];
        const ushort4 t5 = Pb4[(size_t)s5 * CQ + cq];
        const ushort4 t6 = Pb4[(size_t)s6 * CQ + cq];
        const ushort4 t7 = Pb4[(size_t)s7 * CQ + cq];
        addbf4(agg, t0); addbf4(agg, t1); addbf4(agg, t2); addbf4(agg, t3);
        addbf4(agg, t4); addbf4(agg, t5); addbf4(agg, t6); addbf4(agg, t7);
    }
    if (j + 3 < deg) {
        const int s0 = adj[start + j];
        const int s1 = adj[start + j + 1];
        const int s2 = adj[start + j + 2];
        const int s3 = adj[start + j + 3];
        const ushort4 t0 = Pb4[(size_t)s0 * CQ + cq];
        const ushort4 t1 = Pb4[(size_t)s1 * CQ + cq];
        const ushort4 t2 = Pb4[(size_t)s2 * CQ + cq];
        const ushort4 t3 = Pb4[(size_t)s3 * CQ + cq];
        addbf4(agg, t0); addbf4(agg, t1); addbf4(agg, t2); addbf4(agg, t3);
        j += 4;
    }
    for (; j < deg; ++j)
        addbf4(agg, Pb4[(size_t)adj[start + j] * CQ + cq]);

    float4 acc = bv;
#pragma unroll
    for (int k4 = 0; k4 < 8; ++k4) {
        float4 pv = pr[k4];
        fma_step(acc, pv.x, Ws[(4 * k4 + 0) * CQ + cq]);
        fma_step(acc, pv.y, Ws[(4 * k4 + 1) * CQ + cq]);
        fma_step(acc, pv.z, Ws[(4 * k4 + 2) * CQ + cq]);
        fma_step(acc, pv.w, Ws[(4 * k4 + 3) * CQ + cq]);
    }
    {
        float4 pv = pr[cq];
        add4(agg, pv);
        agg.x *= inv; agg.y *= inv; agg.z *= inv; agg.w *= inv;
    }
    Ag[ns][cq] = agg;
    __syncthreads();
#pragma unroll
    for (int k4 = 0; k4 < 8; ++k4) {
        float4 av = Ag[ns][k4];
        fma_step(acc, av.x, Ws[(32 + 4 * k4 + 0) * CQ + cq]);
        fma_step(acc, av.y, Ws[(32 + 4 * k4 + 1) * CQ + cq]);
        fma_step(acc, av.z, Ws[(32 + 4 * k4 + 2) * CQ + cq]);
        fma_step(acc, av.w, Ws[(32 + 4 * k4 + 3) * CQ + cq]);
    }
    float v = fmaxf(acc.x, 0.0f) * wlv.x + fmaxf(acc.y, 0.0f) * wlv.y
            + fmaxf(acc.z, 0.0f) * wlv.z + fmaxf(acc.w, 0.0f) * wlv.w;
    v += __shfl_xor(v, 4, 8);
    v += __shfl_xor(v, 2, 8);
    v += __shfl_xor(v, 1, 8);
    if (cq == 0) out[node] = v + blv;
}

extern "C" void kernel_launch(void* const* d_in, const int* in_sizes, int n_in,
                              void* d_out, int out_size, void* d_ws, size_t ws_size,
                              hipStream_t stream) {
    const float* x    = (const float*)d_in[0];
    const int*   eraw = (const int*)d_in[1];
    const float* W2_1 = (const float*)d_in[2];
    const float* b2_1 = (const float*)d_in[3];
    const float* W1_1 = (const float*)d_in[4];
    const float* b1_1 = (const float*)d_in[5];
    const float* W2_2 = (const float*)d_in[6];
    const float* b2_2 = (const float*)d_in[7];
    const float* W1_2 = (const float*)d_in[8];
    const float* b1_2 = (const float*)d_in[9];
    const float* Wl   = (const float*)d_in[10];
    const float* bl   = (const float*)d_in[11];
    float* out = (float*)d_out;

    // workspace layout (~97 MB)
    char* ws = (char*)d_ws;
    int* flag   = (int*)ws;
    size_t off = 256;
    int* cursor = (int*)(ws + off); off += sizeof(int) * (size_t)(NBKT + 2);
    off = (off + 255) & ~(size_t)255;
    int* ebkt   = (int*)(ws + off); off += sizeof(int) * (size_t)NBKT * BCAP;  // 12.8 MB
    off = (off + 255) & ~(size_t)255;
    int* adj    = (int*)(ws + off); off += sizeof(int) * (size_t)NBKT * BCAP;  // 12.8 MB
    int* rowptr = (int*)(ws + off); off += sizeof(int) * (size_t)N_NODES;
    int* deg    = (int*)(ws + off); off += sizeof(int) * (size_t)N_NODES;
    off = (off + 255) & ~(size_t)255;
    float* bufA = (float*)(ws + off); off += sizeof(float) * (size_t)N_NODES * 64;  // 25.6 MB
    float* bufC = (float*)(ws + off); off += sizeof(float) * (size_t)N_NODES * 64;  // 25.6 MB
    unsigned short* bufAb = (unsigned short*)(ws + off);
    off += sizeof(unsigned short) * (size_t)N_NODES * 64;                           // 12.8 MB

    hipMemsetAsync(cursor, 0, sizeof(int) * (size_t)(NBKT + 2), stream);

    detect_idx64<<<1, 64, 0, stream>>>((const unsigned int*)eraw, flag);

    // fat A: edge scatter overlapped with gemm tiles [0, GHALF)
    scatter_gemm<<<NSCAT + GHALF, BLK, 0, stream>>>(eraw, flag, cursor, ebkt,
                                                    x, W2_1, b2_1, bufA, bufAb);
    // fat B: csrify overlapped with gemm tiles [GHALF, GTILES)
    csrify_gemm<<<NBKT + GHALF, BLK, 0, stream>>>(cursor, ebkt, adj, rowptr, deg,
                                                  x, W2_1, b2_1, bufA, bufAb);

    // conv1 update
    update_gather<64, 64, 512><<<N_NODES / 32, 512, 0, stream>>>(bufA, bufAb, rowptr, deg, adj, W1_1, b1_1, bufC, N_NODES);

    // conv2 (reuse bufA fp32 + bufAb bf16 for h2pre)
    gemm_bias<64, 32><<<N_NODES / 32, BLK, 0, stream>>>(bufC, W2_2, b2_2, bufA, bufAb, N_NODES);
    update2_final<<<N_NODES / 32, BLK, 0, stream>>>(bufA, bufAb, rowptr, deg, adj, W1_2, b1_2, Wl, bl, out, N_NODES);
}